// Round 1
// baseline (1574.790 us; speedup 1.0000x reference)
//
#include <hip/hip_runtime.h>
#include <hip/hip_bf16.h>

#define DIM 128
#define TNODES 32

// ---------------------------------------------------------------------------
// K1: edge scatter. 32 threads per edge, each handles a float4 chunk (128 f32).
// s[dst] += x[src]; cnt[dst] += 1.
// ---------------------------------------------------------------------------
__global__ __launch_bounds__(256) void scatter_kernel(
    const float* __restrict__ x, const int* __restrict__ ei,
    float* __restrict__ s, float* __restrict__ cnt, int E) {
  int gid = blockIdx.x * blockDim.x + threadIdx.x;
  int e = gid >> 5;
  int l = gid & 31;
  if (e >= E) return;
  int src = ei[e];
  int dst = ei[E + e];
  const float4 v = *reinterpret_cast<const float4*>(x + (size_t)src * DIM + l * 4);
  float* sp = s + (size_t)dst * DIM + l * 4;
  atomicAdd(sp + 0, v.x);
  atomicAdd(sp + 1, v.y);
  atomicAdd(sp + 2, v.z);
  atomicAdd(sp + 3, v.w);
  if (l == 0) atomicAdd(cnt + dst, 1.0f);
}

// ---------------------------------------------------------------------------
// K2: per-node out[h] = relu(agg . Wl[:,h] + bl[h] + x . Wr[:,h]); accumulate
// column sums into ligsum[h]. 32 nodes per 256-thread block; wave w handles
// nodes 8w..8w+7, lane l handles h=l and h=l+64.
// ---------------------------------------------------------------------------
__global__ __launch_bounds__(256) void node_kernel(
    const float* __restrict__ x, const float* __restrict__ s,
    const float* __restrict__ cnt, const float* __restrict__ Wl,
    const float* __restrict__ Wr, const float* __restrict__ bl,
    float* __restrict__ ligsum, int nnodes) {
  __shared__ float s_x[TNODES][DIM];
  __shared__ float s_a[TNODES][DIM];  // already divided by max(cnt,1)

  const int tid = threadIdx.x;
  const int nb = blockIdx.x * TNODES;

  // stage 32 node rows of x and normalized agg
  for (int i = tid; i < TNODES * (DIM / 4); i += 256) {
    int n = i >> 5;           // node within block (DIM/4 == 32 chunks per node)
    int c = (i & 31) << 2;    // float offset
    int node = nb + n;
    float4 xv = make_float4(0.f, 0.f, 0.f, 0.f);
    float4 av = make_float4(0.f, 0.f, 0.f, 0.f);
    if (node < nnodes) {
      xv = *reinterpret_cast<const float4*>(x + (size_t)node * DIM + c);
      av = *reinterpret_cast<const float4*>(s + (size_t)node * DIM + c);
      float r = 1.0f / fmaxf(cnt[node], 1.0f);
      av.x *= r; av.y *= r; av.z *= r; av.w *= r;
    }
    *reinterpret_cast<float4*>(&s_x[n][c]) = xv;
    *reinterpret_cast<float4*>(&s_a[n][c]) = av;
  }
  __syncthreads();

  const int wave = tid >> 6;     // 0..3
  const int lane = tid & 63;
  const int n0 = wave * 8;       // 8 nodes per wave
  const int h0 = lane;
  const int h1 = lane + 64;

  float acc[8][2];
#pragma unroll
  for (int n = 0; n < 8; ++n) { acc[n][0] = 0.f; acc[n][1] = 0.f; }

  for (int k4 = 0; k4 < DIM / 4; ++k4) {
    const int k = k4 * 4;
    float wl[4][2], wr[4][2];
#pragma unroll
    for (int kk = 0; kk < 4; ++kk) {
      wl[kk][0] = Wl[(k + kk) * DIM + h0];
      wl[kk][1] = Wl[(k + kk) * DIM + h1];
      wr[kk][0] = Wr[(k + kk) * DIM + h0];
      wr[kk][1] = Wr[(k + kk) * DIM + h1];
    }
#pragma unroll
    for (int n = 0; n < 8; ++n) {
      float4 a4 = *reinterpret_cast<const float4*>(&s_a[n0 + n][k]);
      float4 x4 = *reinterpret_cast<const float4*>(&s_x[n0 + n][k]);
      float av[4] = {a4.x, a4.y, a4.z, a4.w};
      float xv[4] = {x4.x, x4.y, x4.z, x4.w};
#pragma unroll
      for (int kk = 0; kk < 4; ++kk) {
        acc[n][0] = fmaf(av[kk], wl[kk][0], acc[n][0]);
        acc[n][0] = fmaf(xv[kk], wr[kk][0], acc[n][0]);
        acc[n][1] = fmaf(av[kk], wl[kk][1], acc[n][1]);
        acc[n][1] = fmaf(xv[kk], wr[kk][1], acc[n][1]);
      }
    }
  }

  const float b0 = bl[h0];
  const float b1 = bl[h1];
  float cs0 = 0.f, cs1 = 0.f;
#pragma unroll
  for (int n = 0; n < 8; ++n) {
    if (nb + n0 + n < nnodes) {
      cs0 += fmaxf(acc[n][0] + b0, 0.f);
      cs1 += fmaxf(acc[n][1] + b1, 0.f);
    }
  }
  atomicAdd(&ligsum[h0], cs0);
  atomicAdd(&ligsum[h1], cs1);
}

// ---------------------------------------------------------------------------
// K3: out = (ligsum / N) . W_out + b_out   (scalar)
// ---------------------------------------------------------------------------
__global__ void final_kernel(const float* __restrict__ ligsum,
                             const float* __restrict__ Wout,
                             const float* __restrict__ bout,
                             float* __restrict__ out, int nnodes) {
  int l = threadIdx.x;  // 64 threads, one wave
  float v = ligsum[l] * Wout[l] + ligsum[l + 64] * Wout[l + 64];
#pragma unroll
  for (int off = 32; off > 0; off >>= 1) v += __shfl_down(v, off);
  if (l == 0) out[0] = v / (float)nnodes + bout[0];
}

extern "C" void kernel_launch(void* const* d_in, const int* in_sizes, int n_in,
                              void* d_out, int out_size, void* d_ws, size_t ws_size,
                              hipStream_t stream) {
  const float* x    = (const float*)d_in[0];   // x_ligand [N,128]
  const int*   ei   = (const int*)d_in[4];     // ei_ll [2,E]
  const float* Wl   = (const float*)d_in[11];  // Wl_ll [128,128]
  const float* bl   = (const float*)d_in[12];  // bl_ll [128]
  const float* Wr   = (const float*)d_in[13];  // Wr_ll [128,128]
  const float* Wout = (const float*)d_in[14];  // W_out [128,1]
  const float* bout = (const float*)d_in[15];  // b_out [1]

  const int nnodes = in_sizes[0] / DIM;
  const int E = in_sizes[4] / 2;

  float* s   = (float*)d_ws;                    // [N,128] segment sums
  float* cnt = s + (size_t)nnodes * DIM;        // [N]
  float* lig = cnt + nnodes;                    // [128] column sums

  size_t zero_bytes = ((size_t)nnodes * DIM + nnodes + DIM) * sizeof(float);
  hipMemsetAsync(d_ws, 0, zero_bytes, stream);

  // K1: one 32-thread group per edge
  long total_threads = (long)E * 32;
  int blocks1 = (int)((total_threads + 255) / 256);
  scatter_kernel<<<blocks1, 256, 0, stream>>>(x, ei, s, cnt, E);

  // K2
  int blocks2 = (nnodes + TNODES - 1) / TNODES;
  node_kernel<<<blocks2, 256, 0, stream>>>(x, s, cnt, Wl, Wr, bl, lig, nnodes);

  // K3
  final_kernel<<<1, 64, 0, stream>>>(lig, Wout, bout, (float*)d_out, nnodes);
}

// Round 2
// 326.466 us; speedup vs baseline: 4.8237x; 4.8237x over previous
//
#include <hip/hip_runtime.h>
#include <hip/hip_bf16.h>

#define DIM 128
#define TNODES 32

// ---------------------------------------------------------------------------
// K1: histogram of dst degrees (int atomics, L2-resident counters)
// ---------------------------------------------------------------------------
__global__ __launch_bounds__(256) void hist_kernel(
    const int* __restrict__ ei, int* __restrict__ cnt, int E) {
  int e = blockIdx.x * blockDim.x + threadIdx.x;
  if (e >= E) return;
  atomicAdd(&cnt[ei[E + e]], 1);
}

// ---------------------------------------------------------------------------
// K2a/b/c: exclusive prefix scan of cnt[n] -> off[n]  (3-kernel standard scan)
// ---------------------------------------------------------------------------
__global__ __launch_bounds__(256) void scan1_kernel(
    const int* __restrict__ cnt, int* __restrict__ scratch,
    int* __restrict__ bsum, int n) {
  __shared__ int tmp[256];
  int gid = blockIdx.x * 256 + threadIdx.x;
  int v = (gid < n) ? cnt[gid] : 0;
  tmp[threadIdx.x] = v;
  __syncthreads();
  for (int off = 1; off < 256; off <<= 1) {
    int t = (threadIdx.x >= off) ? tmp[threadIdx.x - off] : 0;
    __syncthreads();
    tmp[threadIdx.x] += t;
    __syncthreads();
  }
  if (gid < n) scratch[gid] = tmp[threadIdx.x] - v;  // exclusive within block
  if (threadIdx.x == 255) bsum[blockIdx.x] = tmp[255];
}

__global__ __launch_bounds__(256) void scan2_kernel(int* __restrict__ bsum, int nb) {
  __shared__ int tmp[256];
  int v = (threadIdx.x < nb) ? bsum[threadIdx.x] : 0;
  tmp[threadIdx.x] = v;
  __syncthreads();
  for (int off = 1; off < 256; off <<= 1) {
    int t = (threadIdx.x >= off) ? tmp[threadIdx.x - off] : 0;
    __syncthreads();
    tmp[threadIdx.x] += t;
    __syncthreads();
  }
  if (threadIdx.x < nb) bsum[threadIdx.x] = tmp[threadIdx.x] - v;  // exclusive
}

__global__ __launch_bounds__(256) void scan3_kernel(
    const int* __restrict__ scratch, const int* __restrict__ bsum,
    int* __restrict__ off, int n) {
  int gid = blockIdx.x * 256 + threadIdx.x;
  if (gid < n) off[gid] = scratch[gid] + bsum[blockIdx.x];
}

// ---------------------------------------------------------------------------
// K3: fill CSR buckets: bucket[off[dst] + slot] = src
// ---------------------------------------------------------------------------
__global__ __launch_bounds__(256) void fill_kernel(
    const int* __restrict__ ei, const int* __restrict__ off,
    int* __restrict__ fillc, int* __restrict__ bucket, int E) {
  int e = blockIdx.x * blockDim.x + threadIdx.x;
  if (e >= E) return;
  int src = ei[e];
  int dst = ei[E + e];
  int pos = off[dst] + atomicAdd(&fillc[dst], 1);
  bucket[pos] = src;
}

// ---------------------------------------------------------------------------
// K4: fused gather + node GEMM + relu + column-sum.
// 32 nodes per 256-thread block. Gather phase: each wave owns 8 nodes; for
// each node, lanes read float2 of each neighbor row (512B/wave coalesced),
// accumulate mean in registers, stage into LDS. GEMM phase: wave w handles
// nodes 8w..8w+7, lane l handles h=l and h=l+64.
// ---------------------------------------------------------------------------
__global__ __launch_bounds__(256) void node_kernel(
    const float* __restrict__ x, const int* __restrict__ cnt,
    const int* __restrict__ off, const int* __restrict__ bucket,
    const float* __restrict__ Wl, const float* __restrict__ Wr,
    const float* __restrict__ bl, float* __restrict__ ligsum, int nnodes) {
  __shared__ float s_x[TNODES][DIM];
  __shared__ float s_a[TNODES][DIM];

  const int tid = threadIdx.x;
  const int nb = blockIdx.x * TNODES;
  const int wave = tid >> 6;  // 0..3
  const int lane = tid & 63;
  const int n0 = wave * 8;

  // gather + normalize + stage
  for (int n = 0; n < 8; ++n) {
    const int node = nb + n0 + n;
    float2 acc = make_float2(0.f, 0.f);
    float2 xv = make_float2(0.f, 0.f);
    if (node < nnodes) {
      const int deg = cnt[node];
      const int base = off[node];
      int j = 0;
      for (; j + 1 < deg; j += 2) {  // 2-way unroll for load ILP
        int s0 = bucket[base + j];
        int s1 = bucket[base + j + 1];
        float2 v0 = *reinterpret_cast<const float2*>(x + (size_t)s0 * DIM + lane * 2);
        float2 v1 = *reinterpret_cast<const float2*>(x + (size_t)s1 * DIM + lane * 2);
        acc.x += v0.x + v1.x;
        acc.y += v0.y + v1.y;
      }
      if (j < deg) {
        int s0 = bucket[base + j];
        float2 v0 = *reinterpret_cast<const float2*>(x + (size_t)s0 * DIM + lane * 2);
        acc.x += v0.x;
        acc.y += v0.y;
      }
      float r = 1.0f / fmaxf((float)deg, 1.0f);
      acc.x *= r;
      acc.y *= r;
      xv = *reinterpret_cast<const float2*>(x + (size_t)node * DIM + lane * 2);
    }
    *reinterpret_cast<float2*>(&s_x[n0 + n][lane * 2]) = xv;
    *reinterpret_cast<float2*>(&s_a[n0 + n][lane * 2]) = acc;
  }
  __syncthreads();

  const int h0 = lane;
  const int h1 = lane + 64;

  float acc[8][2];
#pragma unroll
  for (int n = 0; n < 8; ++n) { acc[n][0] = 0.f; acc[n][1] = 0.f; }

  for (int k4 = 0; k4 < DIM / 4; ++k4) {
    const int k = k4 * 4;
    float wl[4][2], wr[4][2];
#pragma unroll
    for (int kk = 0; kk < 4; ++kk) {
      wl[kk][0] = Wl[(k + kk) * DIM + h0];
      wl[kk][1] = Wl[(k + kk) * DIM + h1];
      wr[kk][0] = Wr[(k + kk) * DIM + h0];
      wr[kk][1] = Wr[(k + kk) * DIM + h1];
    }
#pragma unroll
    for (int n = 0; n < 8; ++n) {
      float4 a4 = *reinterpret_cast<const float4*>(&s_a[n0 + n][k]);
      float4 x4 = *reinterpret_cast<const float4*>(&s_x[n0 + n][k]);
      float av[4] = {a4.x, a4.y, a4.z, a4.w};
      float xv[4] = {x4.x, x4.y, x4.z, x4.w};
#pragma unroll
      for (int kk = 0; kk < 4; ++kk) {
        acc[n][0] = fmaf(av[kk], wl[kk][0], acc[n][0]);
        acc[n][0] = fmaf(xv[kk], wr[kk][0], acc[n][0]);
        acc[n][1] = fmaf(av[kk], wl[kk][1], acc[n][1]);
        acc[n][1] = fmaf(xv[kk], wr[kk][1], acc[n][1]);
      }
    }
  }

  const float b0 = bl[h0];
  const float b1 = bl[h1];
  float cs0 = 0.f, cs1 = 0.f;
#pragma unroll
  for (int n = 0; n < 8; ++n) {
    if (nb + n0 + n < nnodes) {
      cs0 += fmaxf(acc[n][0] + b0, 0.f);
      cs1 += fmaxf(acc[n][1] + b1, 0.f);
    }
  }
  atomicAdd(&ligsum[h0], cs0);
  atomicAdd(&ligsum[h1], cs1);
}

// ---------------------------------------------------------------------------
// K5: out = (ligsum / N) . W_out + b_out   (scalar)
// ---------------------------------------------------------------------------
__global__ void final_kernel(const float* __restrict__ ligsum,
                             const float* __restrict__ Wout,
                             const float* __restrict__ bout,
                             float* __restrict__ out, int nnodes) {
  int l = threadIdx.x;  // one wave
  float v = ligsum[l] * Wout[l] + ligsum[l + 64] * Wout[l + 64];
#pragma unroll
  for (int offd = 32; offd > 0; offd >>= 1) v += __shfl_down(v, offd);
  if (l == 0) out[0] = v / (float)nnodes + bout[0];
}

extern "C" void kernel_launch(void* const* d_in, const int* in_sizes, int n_in,
                              void* d_out, int out_size, void* d_ws, size_t ws_size,
                              hipStream_t stream) {
  const float* x    = (const float*)d_in[0];   // x_ligand [N,128]
  const int*   ei   = (const int*)d_in[4];     // ei_ll [2,E]
  const float* Wl   = (const float*)d_in[11];  // Wl_ll [128,128]
  const float* bl   = (const float*)d_in[12];  // bl_ll [128]
  const float* Wr   = (const float*)d_in[13];  // Wr_ll [128,128]
  const float* Wout = (const float*)d_in[14];  // W_out [128,1]
  const float* bout = (const float*)d_in[15];  // b_out [1]

  const int nnodes = in_sizes[0] / DIM;
  const int E = in_sizes[4] / 2;

  // ws layout (all int32 except lig): [cnt N][fillc N][lig 128f][off N][scratch N][bsum 256][bucket E]
  int* cnt_i   = (int*)d_ws;
  int* fillc   = cnt_i + nnodes;
  float* lig   = (float*)(fillc + nnodes);
  int* off     = (int*)(lig + DIM);
  int* scratch = off + nnodes;
  int* bsum    = scratch + nnodes;
  int* bucket  = bsum + 256;

  // zero cnt, fillc, lig in one shot (contiguous prefix)
  hipMemsetAsync(d_ws, 0, (size_t)(2 * nnodes) * sizeof(int) + DIM * sizeof(float),
                 stream);

  const int eblocks = (E + 255) / 256;
  hist_kernel<<<eblocks, 256, 0, stream>>>(ei, cnt_i, E);

  const int nblocks = (nnodes + 255) / 256;  // 196 for N=50000
  scan1_kernel<<<nblocks, 256, 0, stream>>>(cnt_i, scratch, bsum, nnodes);
  scan2_kernel<<<1, 256, 0, stream>>>(bsum, nblocks);
  scan3_kernel<<<nblocks, 256, 0, stream>>>(scratch, bsum, off, nnodes);

  fill_kernel<<<eblocks, 256, 0, stream>>>(ei, off, fillc, bucket, E);

  const int blocks2 = (nnodes + TNODES - 1) / TNODES;
  node_kernel<<<blocks2, 256, 0, stream>>>(x, cnt_i, off, bucket, Wl, Wr, bl,
                                           lig, nnodes);

  final_kernel<<<1, 64, 0, stream>>>(lig, Wout, bout, (float*)d_out, nnodes);
}

// Round 3
// 325.744 us; speedup vs baseline: 4.8344x; 1.0022x over previous
//
#include <hip/hip_runtime.h>
#include <hip/hip_bf16.h>

#define DIM 128
#define TNODES 32

// ---------------------------------------------------------------------------
// K1: histogram of dst degrees (int atomics, L2-resident counters)
// ---------------------------------------------------------------------------
__global__ __launch_bounds__(256) void hist_kernel(
    const int* __restrict__ ei, int* __restrict__ cnt, int E) {
  int e = blockIdx.x * blockDim.x + threadIdx.x;
  if (e >= E) return;
  atomicAdd(&cnt[ei[E + e]], 1);
}

// ---------------------------------------------------------------------------
// K2a/b/c: exclusive prefix scan of cnt[n] -> off[n]
// ---------------------------------------------------------------------------
__global__ __launch_bounds__(256) void scan1_kernel(
    const int* __restrict__ cnt, int* __restrict__ scratch,
    int* __restrict__ bsum, int n) {
  __shared__ int tmp[256];
  int gid = blockIdx.x * 256 + threadIdx.x;
  int v = (gid < n) ? cnt[gid] : 0;
  tmp[threadIdx.x] = v;
  __syncthreads();
  for (int off = 1; off < 256; off <<= 1) {
    int t = (threadIdx.x >= off) ? tmp[threadIdx.x - off] : 0;
    __syncthreads();
    tmp[threadIdx.x] += t;
    __syncthreads();
  }
  if (gid < n) scratch[gid] = tmp[threadIdx.x] - v;  // exclusive within block
  if (threadIdx.x == 255) bsum[blockIdx.x] = tmp[255];
}

__global__ __launch_bounds__(256) void scan2_kernel(int* __restrict__ bsum, int nb) {
  __shared__ int tmp[256];
  int v = (threadIdx.x < nb) ? bsum[threadIdx.x] : 0;
  tmp[threadIdx.x] = v;
  __syncthreads();
  for (int off = 1; off < 256; off <<= 1) {
    int t = (threadIdx.x >= off) ? tmp[threadIdx.x - off] : 0;
    __syncthreads();
    tmp[threadIdx.x] += t;
    __syncthreads();
  }
  if (threadIdx.x < nb) bsum[threadIdx.x] = tmp[threadIdx.x] - v;  // exclusive
}

__global__ __launch_bounds__(256) void scan3_kernel(
    const int* __restrict__ scratch, const int* __restrict__ bsum,
    int* __restrict__ off, int n) {
  int gid = blockIdx.x * 256 + threadIdx.x;
  if (gid < n) off[gid] = scratch[gid] + bsum[blockIdx.x];
}

// ---------------------------------------------------------------------------
// K3: fill CSR buckets: bucket[off[dst] + slot] = src
// ---------------------------------------------------------------------------
__global__ __launch_bounds__(256) void fill_kernel(
    const int* __restrict__ ei, const int* __restrict__ off,
    int* __restrict__ fillc, int* __restrict__ bucket, int E) {
  int e = blockIdx.x * blockDim.x + threadIdx.x;
  if (e >= E) return;
  int src = ei[e];
  int dst = ei[E + e];
  int pos = off[dst] + atomicAdd(&fillc[dst], 1);
  bucket[pos] = src;
}

// ---------------------------------------------------------------------------
// K4: mean-aggregation, ONE WAVE PER NODE. Lane l covers dims [2l, 2l+1].
// 4-way unrolled neighbor loop -> 4 outstanding coalesced 512B row reads.
// deg/base are wave-uniform (readfirstlane) -> SGPR-base addressing.
// ---------------------------------------------------------------------------
__global__ __launch_bounds__(256) void agg_kernel(
    const float* __restrict__ x, const int* __restrict__ cnt,
    const int* __restrict__ off, const int* __restrict__ bucket,
    float* __restrict__ agg, int nnodes) {
  const int wid = (blockIdx.x * 256 + threadIdx.x) >> 6;  // node id
  const int lane = threadIdx.x & 63;
  if (wid >= nnodes) return;
  const int deg  = __builtin_amdgcn_readfirstlane(cnt[wid]);
  const int base = __builtin_amdgcn_readfirstlane(off[wid]);

  float2 a0 = make_float2(0.f, 0.f), a1 = a0, a2 = a0, a3 = a0;
  int j = 0;
  for (; j + 3 < deg; j += 4) {
    const int s0 = __builtin_amdgcn_readfirstlane(bucket[base + j]);
    const int s1 = __builtin_amdgcn_readfirstlane(bucket[base + j + 1]);
    const int s2 = __builtin_amdgcn_readfirstlane(bucket[base + j + 2]);
    const int s3 = __builtin_amdgcn_readfirstlane(bucket[base + j + 3]);
    float2 v0 = *reinterpret_cast<const float2*>(x + (size_t)s0 * DIM + lane * 2);
    float2 v1 = *reinterpret_cast<const float2*>(x + (size_t)s1 * DIM + lane * 2);
    float2 v2 = *reinterpret_cast<const float2*>(x + (size_t)s2 * DIM + lane * 2);
    float2 v3 = *reinterpret_cast<const float2*>(x + (size_t)s3 * DIM + lane * 2);
    a0.x += v0.x; a0.y += v0.y;
    a1.x += v1.x; a1.y += v1.y;
    a2.x += v2.x; a2.y += v2.y;
    a3.x += v3.x; a3.y += v3.y;
  }
  for (; j < deg; ++j) {
    const int s0 = __builtin_amdgcn_readfirstlane(bucket[base + j]);
    float2 v0 = *reinterpret_cast<const float2*>(x + (size_t)s0 * DIM + lane * 2);
    a0.x += v0.x; a0.y += v0.y;
  }
  const float r = 1.0f / fmaxf((float)deg, 1.0f);
  float2 out;
  out.x = (a0.x + a1.x + a2.x + a3.x) * r;
  out.y = (a0.y + a1.y + a2.y + a3.y) * r;
  *reinterpret_cast<float2*>(agg + (size_t)wid * DIM + lane * 2) = out;
}

// ---------------------------------------------------------------------------
// K5: node GEMM + relu + column-sum. 32 nodes/block staged to LDS; wave w
// handles nodes 8w..8w+7; lane l handles h=l and h=l+64.
// ---------------------------------------------------------------------------
__global__ __launch_bounds__(256) void gemm_kernel(
    const float* __restrict__ x, const float* __restrict__ agg,
    const float* __restrict__ Wl, const float* __restrict__ Wr,
    const float* __restrict__ bl, float* __restrict__ ligsum, int nnodes) {
  __shared__ float s_x[TNODES][DIM];
  __shared__ float s_a[TNODES][DIM];

  const int tid = threadIdx.x;
  const int nb = blockIdx.x * TNODES;

  for (int i = tid; i < TNODES * (DIM / 4); i += 256) {
    int n = i >> 5;
    int c = (i & 31) << 2;
    int node = nb + n;
    float4 xv = make_float4(0.f, 0.f, 0.f, 0.f);
    float4 av = make_float4(0.f, 0.f, 0.f, 0.f);
    if (node < nnodes) {
      xv = *reinterpret_cast<const float4*>(x + (size_t)node * DIM + c);
      av = *reinterpret_cast<const float4*>(agg + (size_t)node * DIM + c);
    }
    *reinterpret_cast<float4*>(&s_x[n][c]) = xv;
    *reinterpret_cast<float4*>(&s_a[n][c]) = av;
  }
  __syncthreads();

  const int wave = tid >> 6;
  const int lane = tid & 63;
  const int n0 = wave * 8;
  const int h0 = lane;
  const int h1 = lane + 64;

  float acc[8][2];
#pragma unroll
  for (int n = 0; n < 8; ++n) { acc[n][0] = 0.f; acc[n][1] = 0.f; }

  for (int k4 = 0; k4 < DIM / 4; ++k4) {
    const int k = k4 * 4;
    float wl[4][2], wr[4][2];
#pragma unroll
    for (int kk = 0; kk < 4; ++kk) {
      wl[kk][0] = Wl[(k + kk) * DIM + h0];
      wl[kk][1] = Wl[(k + kk) * DIM + h1];
      wr[kk][0] = Wr[(k + kk) * DIM + h0];
      wr[kk][1] = Wr[(k + kk) * DIM + h1];
    }
#pragma unroll
    for (int n = 0; n < 8; ++n) {
      float4 a4 = *reinterpret_cast<const float4*>(&s_a[n0 + n][k]);
      float4 x4 = *reinterpret_cast<const float4*>(&s_x[n0 + n][k]);
      float av[4] = {a4.x, a4.y, a4.z, a4.w};
      float xv[4] = {x4.x, x4.y, x4.z, x4.w};
#pragma unroll
      for (int kk = 0; kk < 4; ++kk) {
        acc[n][0] = fmaf(av[kk], wl[kk][0], acc[n][0]);
        acc[n][0] = fmaf(xv[kk], wr[kk][0], acc[n][0]);
        acc[n][1] = fmaf(av[kk], wl[kk][1], acc[n][1]);
        acc[n][1] = fmaf(xv[kk], wr[kk][1], acc[n][1]);
      }
    }
  }

  const float b0 = bl[h0];
  const float b1 = bl[h1];
  float cs0 = 0.f, cs1 = 0.f;
#pragma unroll
  for (int n = 0; n < 8; ++n) {
    if (nb + n0 + n < nnodes) {
      cs0 += fmaxf(acc[n][0] + b0, 0.f);
      cs1 += fmaxf(acc[n][1] + b1, 0.f);
    }
  }
  atomicAdd(&ligsum[h0], cs0);
  atomicAdd(&ligsum[h1], cs1);
}

// ---------------------------------------------------------------------------
// K6: out = (ligsum / N) . W_out + b_out   (scalar)
// ---------------------------------------------------------------------------
__global__ void final_kernel(const float* __restrict__ ligsum,
                             const float* __restrict__ Wout,
                             const float* __restrict__ bout,
                             float* __restrict__ out, int nnodes) {
  int l = threadIdx.x;  // one wave
  float v = ligsum[l] * Wout[l] + ligsum[l + 64] * Wout[l + 64];
#pragma unroll
  for (int offd = 32; offd > 0; offd >>= 1) v += __shfl_down(v, offd);
  if (l == 0) out[0] = v / (float)nnodes + bout[0];
}

extern "C" void kernel_launch(void* const* d_in, const int* in_sizes, int n_in,
                              void* d_out, int out_size, void* d_ws, size_t ws_size,
                              hipStream_t stream) {
  const float* x    = (const float*)d_in[0];   // x_ligand [N,128]
  const int*   ei   = (const int*)d_in[4];     // ei_ll [2,E]
  const float* Wl   = (const float*)d_in[11];  // Wl_ll [128,128]
  const float* bl   = (const float*)d_in[12];  // bl_ll [128]
  const float* Wr   = (const float*)d_in[13];  // Wr_ll [128,128]
  const float* Wout = (const float*)d_in[14];  // W_out [128,1]
  const float* bout = (const float*)d_in[15];  // b_out [1]

  const int nnodes = in_sizes[0] / DIM;
  const int E = in_sizes[4] / 2;

  // ws layout: [cnt N][fillc N][lig 128f][off N][scratch N][bsum 256][bucket E][agg N*128f]
  int* cnt_i   = (int*)d_ws;
  int* fillc   = cnt_i + nnodes;
  float* lig   = (float*)(fillc + nnodes);
  int* off     = (int*)(lig + DIM);
  int* scratch = off + nnodes;
  int* bsum    = scratch + nnodes;
  int* bucket  = bsum + 256;
  float* agg   = (float*)(bucket + E);

  // zero cnt, fillc, lig (contiguous prefix)
  hipMemsetAsync(d_ws, 0, (size_t)(2 * nnodes) * sizeof(int) + DIM * sizeof(float),
                 stream);

  const int eblocks = (E + 255) / 256;
  hist_kernel<<<eblocks, 256, 0, stream>>>(ei, cnt_i, E);

  const int nblocks = (nnodes + 255) / 256;
  scan1_kernel<<<nblocks, 256, 0, stream>>>(cnt_i, scratch, bsum, nnodes);
  scan2_kernel<<<1, 256, 0, stream>>>(bsum, nblocks);
  scan3_kernel<<<nblocks, 256, 0, stream>>>(scratch, bsum, off, nnodes);

  fill_kernel<<<eblocks, 256, 0, stream>>>(ei, off, fillc, bucket, E);

  const int ablocks = (nnodes + 3) / 4;  // 4 waves/block, 1 node/wave
  agg_kernel<<<ablocks, 256, 0, stream>>>(x, cnt_i, off, bucket, agg, nnodes);

  const int gblocks = (nnodes + TNODES - 1) / TNODES;
  gemm_kernel<<<gblocks, 256, 0, stream>>>(x, agg, Wl, Wr, bl, lig, nnodes);

  final_kernel<<<1, 64, 0, stream>>>(lig, Wout, bout, (float*)d_out, nnodes);
}